// Round 1
// baseline (227.282 us; speedup 1.0000x reference)
//
#include <hip/hip_runtime.h>

// SNN conv layer: 3x3x16->64 conv (SAME, stride 1) on 512x512 NHWC,
// + old_potentials, threshold 1.0 -> (spikes, reset potentials).
// fp32 direct conv, LDS staged, 8px x 8ch register tile per thread.

#define H 512
#define W 512
#define CI 16
#define CO 64
#define TX 32           // block x-pixel tile
#define TY 8            // block y-pixel tile
#define LDS_XS 36       // padded x stride for input tile (34 used)

__global__ __launch_bounds__(256, 2)
void snn_conv_kernel(const float* __restrict__ in,
                     const float* __restrict__ w,
                     const float* __restrict__ oldp,
                     float* __restrict__ out_spk,
                     float* __restrict__ out_pot)
{
    // input tile: rows [ty0-1, ty0+TY], x [tx0-1, tx0+TX], layout [y][ci][x]
    __shared__ float s_in[(TY + 2) * CI * LDS_XS];   // 10*16*36 = 5760 floats
    __shared__ float s_w[9 * CI * CO];               // 9216 floats

    const int tid = threadIdx.x;
    const int bx = blockIdx.x & 15;        // 512/32 = 16 tiles in x
    const int by = blockIdx.x >> 4;        // 64 tiles in y
    const int tx0 = bx * TX;
    const int ty0 = by * TY;

    // ---- stage weights: 9216 floats = 2304 float4, 9 per thread, coalesced
    {
        const float4* wsrc = (const float4*)w;
        float4* wdst = (float4*)s_w;
        #pragma unroll
        for (int i = 0; i < 9; ++i)
            wdst[tid + i * 256] = wsrc[tid + i * 256];
    }

    // ---- stage input tile with NHWC -> [y][ci][x] transpose, zero halo
    for (int idx = tid; idx < (TY + 2) * (TX + 2); idx += 256) {
        const int ly = idx / (TX + 2);
        const int lx = idx - ly * (TX + 2);
        const int gy = ty0 + ly - 1;
        const int gx = tx0 + lx - 1;
        float4 v[4];
        if (gy >= 0 && gy < H && gx >= 0 && gx < W) {
            const float4* p = (const float4*)(in + (gy * W + gx) * CI);
            v[0] = p[0]; v[1] = p[1]; v[2] = p[2]; v[3] = p[3];
        } else {
            v[0] = v[1] = v[2] = v[3] = make_float4(0.f, 0.f, 0.f, 0.f);
        }
        const float* t = (const float*)v;
        float* dst = s_in + ly * (CI * LDS_XS) + lx;
        #pragma unroll
        for (int c = 0; c < CI; ++c)
            dst[c * LDS_XS] = t[c];     // stride 36 -> 2-way bank alias (free)
    }
    __syncthreads();

    // ---- thread mapping: 8 consecutive x-pixels x 8 channels
    const int cog = (tid & 7) * 8;         // output-channel base
    const int pg  = tid >> 3;              // 0..31 pixel group
    const int px  = (pg & 3) * 8;          // x sub-tile base within block tile
    const int py  = pg >> 2;               // 0..7 row within block tile

    float acc[8][8];
    #pragma unroll
    for (int xi = 0; xi < 8; ++xi)
        #pragma unroll
        for (int c = 0; c < 8; ++c)
            acc[xi][c] = 0.f;

    for (int ky = 0; ky < 3; ++ky) {
        const float* irow = s_in + (py + ky) * (CI * LDS_XS) + px;
        const float* wrow = s_w + ky * 3 * CI * CO + cog;
        #pragma unroll 1
        for (int ci = 0; ci < CI; ++ci) {
            const float* ir = irow + ci * LDS_XS;
            float iv[10];
            *(float4*)&iv[0] = *(const float4*)(ir);
            *(float4*)&iv[4] = *(const float4*)(ir + 4);
            iv[8] = ir[8];
            iv[9] = ir[9];
            const float* wr = wrow + ci * CO;
            #pragma unroll
            for (int kx = 0; kx < 3; ++kx) {
                float wv[8];
                *(float4*)&wv[0] = *(const float4*)(wr + kx * CI * CO);
                *(float4*)&wv[4] = *(const float4*)(wr + kx * CI * CO + 4);
                #pragma unroll
                for (int xi = 0; xi < 8; ++xi)
                    #pragma unroll
                    for (int c = 0; c < 8; ++c)
                        acc[xi][c] = fmaf(iv[xi + kx], wv[c], acc[xi][c]);
            }
        }
    }

    // ---- epilogue: add old potential, threshold, spike + reset
    const int gy = ty0 + py;
    #pragma unroll
    for (int xi = 0; xi < 8; ++xi) {
        const int gx = tx0 + px + xi;
        const int base = (gy * W + gx) * CO + cog;
        float old[8];
        *(float4*)&old[0] = *(const float4*)(oldp + base);
        *(float4*)&old[4] = *(const float4*)(oldp + base + 4);
        float spk[8], pot[8];
        #pragma unroll
        for (int c = 0; c < 8; ++c) {
            const float np = acc[xi][c] + old[c];
            const bool s = (np >= 1.0f);
            spk[c] = s ? 1.0f : 0.0f;
            pot[c] = s ? 0.0f : np;
        }
        *(float4*)(out_spk + base)     = *(const float4*)&spk[0];
        *(float4*)(out_spk + base + 4) = *(const float4*)&spk[4];
        *(float4*)(out_pot + base)     = *(const float4*)&pot[0];
        *(float4*)(out_pot + base + 4) = *(const float4*)&pot[4];
    }
}

extern "C" void kernel_launch(void* const* d_in, const int* in_sizes, int n_in,
                              void* d_out, int out_size, void* d_ws, size_t ws_size,
                              hipStream_t stream) {
    const float* in   = (const float*)d_in[0];   // (1,512,512,16)
    const float* w    = (const float*)d_in[1];   // (3,3,16,64)
    const float* oldp = (const float*)d_in[2];   // (1,512,512,64)
    float* out_spk = (float*)d_out;              // (1,512,512,64) spikes
    float* out_pot = out_spk + (size_t)H * W * CO; // (1,512,512,64) new potentials

    const int grid = (W / TX) * (H / TY);        // 16 * 64 = 1024 blocks
    snn_conv_kernel<<<grid, 256, 0, stream>>>(in, w, oldp, out_spk, out_pot);
}